// Round 10
// baseline (1446.731 us; speedup 1.0000x reference)
//
#include <hip/hip_runtime.h>
#include <stdint.h>

typedef __attribute__((ext_vector_type(8))) short bf16x8;
typedef __attribute__((ext_vector_type(8))) unsigned short u16x8;
typedef __attribute__((ext_vector_type(4))) float f32x4;

#define NB   16
#define CIN  256
#define COUT 256
#define HH   128
#define WW   128
#define SDIM 512

#define KPAD 72        // row pitch 144B = 36 dwords
#define NCOL 130       // cols -1..128 (col 0 and 129 = always-zero w-padding)
#define BHALF (3 * NCOL * KPAD)          // elements per B buffer = 28080
#define B_BYTES (BHALF * 2)              // 56160
#define LDS_BYTES (2 * B_BYTES + COUT * 4)  // 113344
#define NTHR 1024                         // 16 waves -> 4 waves/SIMD, 1 block/CU

__device__ __forceinline__ unsigned short f2bf(float f) {
    unsigned int u = __float_as_uint(f);
    u += 0x7fff + ((u >> 16) & 1);   // round-to-nearest-even
    return (unsigned short)(u >> 16);
}

__global__ void style_fc_kernel(const float* __restrict__ style,
                                const float* __restrict__ fc_w,
                                const float* __restrict__ fc_b,
                                float* __restrict__ s_out) {
    const int b = blockIdx.x;
    const int co = threadIdx.x;
    const f32x4* st = (const f32x4*)(style + b * SDIM);
    const f32x4* w  = (const f32x4*)(fc_w + co * SDIM);
    float acc = fc_b[co];
    #pragma unroll 4
    for (int k = 0; k < SDIM / 4; ++k) {
        f32x4 a = st[k], c = w[k];
        acc += a.x * c.x + a.y * c.y + a.z * c.z + a.w * c.w;
    }
    s_out[b * COUT + co] = acc;
}

// conv_w (Cout,Cin,3,3) f32 -> wt[t][q][co][k] bf16 (t=kh*3+kw, q=ci>>6, k=ci&63)
__global__ void wt_transform_kernel(const float* __restrict__ conv_w,
                                    unsigned short* __restrict__ wt) {
    __shared__ unsigned short T[9][256];
    const int co = blockIdx.x;
    const int ci = threadIdx.x;
    const float* src = conv_w + ((size_t)co * CIN + ci) * 9;
    float v[9];
    #pragma unroll
    for (int t = 0; t < 9; ++t) v[t] = src[t];
    #pragma unroll
    for (int t = 0; t < 9; ++t) T[t][ci] = f2bf(v[t]);
    __syncthreads();
    const unsigned int* T32 = (const unsigned int*)&T[0][0];   // 1152 dwords
    unsigned int* out32 = (unsigned int*)wt;
    for (int idx = ci; idx < 1152; idx += 256) {
        const int d = idx & 31;
        const int r = idx >> 5;                   // r = t*4+q
        out32[(((size_t)r * COUT + co) << 5) + d] = T32[idx];
    }
}

// One block per (b,h). 16 waves (4 co-quads x 4 w-quarters), wave tile 64co x 32w.
// Same per-wave pipeline as r9 (A reg-dbuf, T14 x-prefetch, B LDS-dbuf), 2x the waves/SIMD.
__global__ void __launch_bounds__(NTHR, 4)
modconv_kernel(const float* __restrict__ x,
               const unsigned short* __restrict__ wt,
               const float* __restrict__ s,
               float* __restrict__ out) {
    extern __shared__ char lds[];
    unsigned short* B0 = (unsigned short*)lds;
    unsigned short* B1 = B0 + BHALF;
    float* Sl = (float*)(lds + 2 * B_BYTES);

    const int tid  = threadIdx.x;
    const int lane = tid & 63;
    const int wid  = tid >> 6;
    const int bid  = blockIdx.x;
    const int nid  = (bid & 7) * 256 + (bid >> 3);   // XCD swizzle (bijective, 2048%8==0)
    const int bb   = nid >> 7;
    const int h    = nid & 127;

    // zero both B buffers (covers w-pad cols, OOB h rows, pad tails)
    {
        f32x4 z = {0.f, 0.f, 0.f, 0.f};
        for (int i = tid; i < (2 * B_BYTES) / 16; i += NTHR)
            *(f32x4*)(lds + i * 16) = z;
    }
    if (tid < COUT) Sl[tid] = s[bb * COUT + tid];

    f32x4 acc[4][2];
    {
        f32x4 z = {0.f, 0.f, 0.f, 0.f};
        #pragma unroll
        for (int mi = 0; mi < 4; ++mi)
            #pragma unroll
            for (int nj = 0; nj < 2; ++nj)
                acc[mi][nj] = z;
    }

    const int wm = wid >> 2;          // co quadrant (64 rows)
    const int wn = wid & 3;           // w quarter (32 cols)
    const int cobase = wm * 64;
    const int wbase  = wn * 32;
    const int l15 = lane & 15;
    const int kl8 = (lane >> 4) * 8;
    const int g   = tid >> 7;         // ci-octet for staging (0..7)
    const int c   = tid & 127;        // col for staging

    float xv[3][8];                   // staged x for next q (compile-time indices)

    auto LOADX = [&](int q) {
        #pragma unroll
        for (int kh = 0; kh < 3; ++kh) {
            const int r = h + kh - 1;
            if (r >= 0 && r < HH) {   // block-uniform
                const float* xs = x + (((size_t)(bb * CIN + q * 64 + g * 8)) * HH + r) * WW + c;
                #pragma unroll
                for (int j = 0; j < 8; ++j)
                    xv[kh][j] = xs[j * (HH * WW)];
            } else {
                #pragma unroll
                for (int j = 0; j < 8; ++j)
                    xv[kh][j] = 0.0f;
            }
        }
    };
    auto WRITEX = [&](unsigned short* Bd) {
        #pragma unroll
        for (int kh = 0; kh < 3; ++kh) {
            u16x8 vv;
            #pragma unroll
            for (int j = 0; j < 8; ++j) vv[j] = f2bf(xv[kh][j]);
            *(u16x8*)(Bd + (kh * NCOL + 1 + c) * KPAD + g * 8) = vv;
        }
    };
    auto LOADA = [&](bf16x8* a, int q, int t, int kk) {
        const unsigned short* p = wt + (((size_t)(t * 4 + q) * COUT + cobase + l15) << 6) + kk + kl8;
        #pragma unroll
        for (int mi = 0; mi < 4; ++mi)
            a[mi] = *(const bf16x8*)(p + (mi << 10));    // mi*16 rows * 64
    };
    auto LOADB = [&](bf16x8* b, const unsigned short* Bc, int kh, int kw, int kk) {
        #pragma unroll
        for (int nj = 0; nj < 2; ++nj)
            b[nj] = *(const bf16x8*)(Bc + (kh * NCOL + wbase + nj * 16 + l15 + kw) * KPAD + kk + kl8);
    };

    __syncthreads();                  // zeros + Sl visible
    LOADX(0);
    WRITEX(B0);
    __syncthreads();                  // B0 ready

    bf16x8 aA[4], aB[4];
    LOADA(aA, 0, 0, 0);

    #pragma unroll 1
    for (int q = 0; q < 4; ++q) {
        unsigned short* Bc = (q & 1) ? B1 : B0;
        unsigned short* Bn = (q & 1) ? B0 : B1;
        if (q < 3) LOADX(q + 1);      // T14: issue early, consumed after taps
        const int qn = (q < 3) ? q + 1 : 3;

        #pragma unroll
        for (int t = 0; t < 9; ++t) {
            const int kh = t / 3;
            const int kw = t - kh * 3;
            bf16x8 b[2];
            // sub-step 0: compute with aA, prefetch aB <- (t, kk=32)
            LOADB(b, Bc, kh, kw, 0);
            LOADA(aB, q, t, 32);
            #pragma unroll
            for (int mi = 0; mi < 4; ++mi)
                #pragma unroll
                for (int nj = 0; nj < 2; ++nj)
                    acc[mi][nj] = __builtin_amdgcn_mfma_f32_16x16x32_bf16(
                        aA[mi], b[nj], acc[mi][nj], 0, 0, 0);
            // sub-step 1: compute with aB, prefetch aA <- next (t+1,0) / next-q (0,0)
            LOADB(b, Bc, kh, kw, 32);
            if (t < 8) LOADA(aA, q, t + 1, 0);
            else       LOADA(aA, qn, 0, 0);
            #pragma unroll
            for (int mi = 0; mi < 4; ++mi)
                #pragma unroll
                for (int nj = 0; nj < 2; ++nj)
                    acc[mi][nj] = __builtin_amdgcn_mfma_f32_16x16x32_bf16(
                        aB[mi], b[nj], acc[mi][nj], 0, 0, 0);
        }

        if (q < 3) {
            WRITEX(Bn);               // consumes the early LOADX via data dep
            __syncthreads();          // Bn ready; all readers of Bc done
        }
    }

    // epilogue: scale by s[b,co], store f32
    const int rowD = (lane >> 4) * 4;
    #pragma unroll
    for (int mi = 0; mi < 4; ++mi) {
        #pragma unroll
        for (int r = 0; r < 4; ++r) {
            const int co = cobase + mi * 16 + rowD + r;
            const float sv = Sl[co];
            float* orow = out + (((size_t)(bb * COUT + co) * HH + h) * WW);
            #pragma unroll
            for (int nj = 0; nj < 2; ++nj)
                orow[wbase + nj * 16 + l15] = acc[mi][nj][r] * sv;
        }
    }
}

extern "C" void kernel_launch(void* const* d_in, const int* in_sizes, int n_in,
                              void* d_out, int out_size, void* d_ws, size_t ws_size,
                              hipStream_t stream) {
    const float* x      = (const float*)d_in[0];
    const float* style  = (const float*)d_in[1];
    const float* conv_w = (const float*)d_in[2];
    const float* fc_w   = (const float*)d_in[3];
    const float* fc_b   = (const float*)d_in[4];
    float* out = (float*)d_out;

    float* s_ws = (float*)d_ws;                                   // 16KB
    unsigned short* wt = (unsigned short*)((char*)d_ws + 16384);  // 1.125 MB

    hipFuncSetAttribute(reinterpret_cast<const void*>(modconv_kernel),
                        hipFuncAttributeMaxDynamicSharedMemorySize, LDS_BYTES);

    style_fc_kernel<<<NB, COUT, 0, stream>>>(style, fc_w, fc_b, s_ws);
    wt_transform_kernel<<<COUT, 256, 0, stream>>>(conv_w, wt);
    modconv_kernel<<<NB * HH, NTHR, LDS_BYTES, stream>>>(x, wt, s_ws, out);
}

// Round 12
// 843.794 us; speedup vs baseline: 1.7146x; 1.7146x over previous
//
#include <hip/hip_runtime.h>
#include <stdint.h>

typedef __attribute__((ext_vector_type(8))) short bf16x8;
typedef __attribute__((ext_vector_type(8))) unsigned short u16x8;
typedef __attribute__((ext_vector_type(4))) float f32x4;

#define NB   16
#define CIN  256
#define COUT 256
#define HH   128
#define WW   128
#define SDIM 512

#define KPAD 72        // row pitch 144B; consecutive lanes conflict-free on b128 write
#define NCOL 130       // cols -1..128 (col 0 and 129 = always-zero w-padding)
#define BROWS 4        // h0-1 .. h0+2
#define B_BYTES (BROWS * NCOL * KPAD * 2)   // 74880
#define LDS_BYTES (B_BYTES + COUT * 4)      // 75904
#define NBLK (NB * (HH / 2))                // 1024 blocks

__device__ __forceinline__ unsigned short f2bf(float f) {
    unsigned int u = __float_as_uint(f);
    u += 0x7fff + ((u >> 16) & 1);   // round-to-nearest-even
    return (unsigned short)(u >> 16);
}

__global__ void style_fc_kernel(const float* __restrict__ style,
                                const float* __restrict__ fc_w,
                                const float* __restrict__ fc_b,
                                float* __restrict__ s_out) {
    const int b = blockIdx.x;
    const int co = threadIdx.x;
    const f32x4* st = (const f32x4*)(style + b * SDIM);
    const f32x4* w  = (const f32x4*)(fc_w + co * SDIM);
    float acc = fc_b[co];
    #pragma unroll 4
    for (int k = 0; k < SDIM / 4; ++k) {
        f32x4 a = st[k], c = w[k];
        acc += a.x * c.x + a.y * c.y + a.z * c.z + a.w * c.w;
    }
    s_out[b * COUT + co] = acc;
}

// conv_w (Cout,Cin,3,3) f32 -> wt[t][q][co][k] bf16 (t=kh*3+kw, q=ci>>6, k=ci&63)
__global__ void wt_transform_kernel(const float* __restrict__ conv_w,
                                    unsigned short* __restrict__ wt) {
    __shared__ unsigned short T[9][256];
    const int co = blockIdx.x;
    const int ci = threadIdx.x;
    const float* src = conv_w + ((size_t)co * CIN + ci) * 9;
    float v[9];
    #pragma unroll
    for (int t = 0; t < 9; ++t) v[t] = src[t];
    #pragma unroll
    for (int t = 0; t < 9; ++t) T[t][ci] = f2bf(v[t]);
    __syncthreads();
    const unsigned int* T32 = (const unsigned int*)&T[0][0];   // 1152 dwords
    unsigned int* out32 = (unsigned int*)wt;
    for (int idx = ci; idx < 1152; idx += 256) {
        const int d = idx & 31;
        const int r = idx >> 5;                   // r = t*4+q
        out32[(((size_t)r * COUT + co) << 5) + d] = T32[idx];
    }
}

// One block per (b, h-pair): out[b, 0:256, h0:h0+2, 0:128].
// 8 waves, wave tile 64co x 64w x 2h -> 32 MFMAs per substep vs 4 A-frag loads:
// 2x MFMA-work per A-byte vs r9 (A L2-traffic was the measured bottleneck).
__global__ void __launch_bounds__(512, 2)
modconv_kernel(const float* __restrict__ x,
               const unsigned short* __restrict__ wt,
               const float* __restrict__ s,
               float* __restrict__ out) {
    extern __shared__ char lds[];
    unsigned short* Bl = (unsigned short*)lds;     // [4][130][72]
    float* Sl = (float*)(lds + B_BYTES);

    const int tid  = threadIdx.x;
    const int lane = tid & 63;
    const int wid  = tid >> 6;
    const int bid  = blockIdx.x;
    const int nid  = (bid & 7) * (NBLK / 8) + (bid >> 3);  // XCD swizzle, bijective
    const int bb   = nid >> 6;
    const int h0   = (nid & 63) * 2;

    // zero B tile (covers w-pad cols, OOB h rows, k-pad tail)
    {
        f32x4 z = {0.f, 0.f, 0.f, 0.f};
        for (int i = tid; i < B_BYTES / 16; i += 512)
            *(f32x4*)(lds + i * 16) = z;
    }
    if (tid < COUT) Sl[tid] = s[bb * COUT + tid];

    f32x4 acc[4][4][2];   // [mi co-frag][nj w-frag][hh]
    {
        f32x4 z = {0.f, 0.f, 0.f, 0.f};
        #pragma unroll
        for (int mi = 0; mi < 4; ++mi)
            #pragma unroll
            for (int nj = 0; nj < 4; ++nj)
                #pragma unroll
                for (int hh = 0; hh < 2; ++hh)
                    acc[mi][nj][hh] = z;
    }

    const int wm = wid >> 1;          // co quadrant
    const int wn = wid & 1;           // w half
    const int cobase = wm * 64;
    const int wbase  = wn * 64;
    const int l15 = lane & 15;
    const int kl8 = (lane >> 4) * 8;
    const int p  = tid >> 7;          // 0..3 staging row-group
    const int c  = tid & 127;         // staging col

    // stage B for chunk q: rows h0-1..h0+2, 64 ci as 8 octets (p, p+4)
    auto STAGE = [&](int q) {
        #pragma unroll
        for (int rr = 0; rr < BROWS; ++rr) {
            const int r = h0 - 1 + rr;
            if (r >= 0 && r < HH) {   // block-uniform
                #pragma unroll
                for (int jj = 0; jj < 2; ++jj) {
                    const int o = p + jj * 4;   // ci octet 0..7
                    const float* xs = x + (((size_t)(bb * CIN + q * 64 + o * 8)) * HH + r) * WW + c;
                    u16x8 vv;
                    #pragma unroll
                    for (int j = 0; j < 8; ++j)
                        vv[j] = f2bf(xs[j * (HH * WW)]);   // coalesced 256B/wave
                    *(u16x8*)(Bl + (rr * NCOL + 1 + c) * KPAD + o * 8) = vv;
                }
            }
        }
    };
    auto LOADA = [&](bf16x8* a, int q, int t, int kk) {
        const unsigned short* ptr = wt + (((size_t)(t * 4 + q) * COUT + cobase + l15) << 6) + kk + kl8;
        #pragma unroll
        for (int mi = 0; mi < 4; ++mi)
            a[mi] = *(const bf16x8*)(ptr + (mi << 10));    // mi*16 rows * 64
    };
    auto LOADB8 = [&](bf16x8* b, int kh, int kw, int kk) {
        #pragma unroll
        for (int hh = 0; hh < 2; ++hh)
            #pragma unroll
            for (int nj = 0; nj < 4; ++nj)
                b[hh * 4 + nj] = *(const bf16x8*)(Bl + ((kh + hh) * NCOL + wbase + nj * 16 + l15 + kw) * KPAD + kk + kl8);
    };

    __syncthreads();                  // zeros + Sl visible
    STAGE(0);
    __syncthreads();                  // B(q=0) ready

    bf16x8 aA[4], aB[4];
    LOADA(aA, 0, 0, 0);

    #pragma unroll 1
    for (int q = 0; q < 4; ++q) {
        const int qn = (q < 3) ? q + 1 : 3;
        #pragma unroll
        for (int t = 0; t < 9; ++t) {
            const int kh = t / 3;
            const int kw = t - kh * 3;
            bf16x8 b[8];
            // sub-step 0: compute with aA, prefetch aB <- (t, kk=32)
            LOADB8(b, kh, kw, 0);
            LOADA(aB, q, t, 32);
            #pragma unroll
            for (int mi = 0; mi < 4; ++mi)
                #pragma unroll
                for (int hh = 0; hh < 2; ++hh)
                    #pragma unroll
                    for (int nj = 0; nj < 4; ++nj)
                        acc[mi][nj][hh] = __builtin_amdgcn_mfma_f32_16x16x32_bf16(
                            aA[mi], b[hh * 4 + nj], acc[mi][nj][hh], 0, 0, 0);
            // sub-step 1: compute with aB, prefetch aA <- next (t+1,0) / next-q (0,0)
            LOADB8(b, kh, kw, 32);
            if (t < 8) LOADA(aA, q, t + 1, 0);
            else       LOADA(aA, qn, 0, 0);
            #pragma unroll
            for (int mi = 0; mi < 4; ++mi)
                #pragma unroll
                for (int hh = 0; hh < 2; ++hh)
                    #pragma unroll
                    for (int nj = 0; nj < 4; ++nj)
                        acc[mi][nj][hh] = __builtin_amdgcn_mfma_f32_16x16x32_bf16(
                            aB[mi], b[hh * 4 + nj], acc[mi][nj][hh], 0, 0, 0);
        }
        if (q < 3) {
            __syncthreads();          // all waves done reading B(q)
            STAGE(q + 1);
            __syncthreads();          // B(q+1) ready
        }
    }

    // epilogue: scale by s[b,co], store f32 (2 h-rows)
    const int rowD = (lane >> 4) * 4;
    #pragma unroll
    for (int mi = 0; mi < 4; ++mi) {
        #pragma unroll
        for (int r = 0; r < 4; ++r) {
            const int co = cobase + mi * 16 + rowD + r;
            const float sv = Sl[co];
            #pragma unroll
            for (int hh = 0; hh < 2; ++hh) {
                float* orow = out + (((size_t)(bb * COUT + co) * HH + h0 + hh) * WW);
                #pragma unroll
                for (int nj = 0; nj < 4; ++nj)
                    orow[wbase + nj * 16 + l15] = acc[mi][nj][hh][r] * sv;
            }
        }
    }
}

extern "C" void kernel_launch(void* const* d_in, const int* in_sizes, int n_in,
                              void* d_out, int out_size, void* d_ws, size_t ws_size,
                              hipStream_t stream) {
    const float* x      = (const float*)d_in[0];
    const float* style  = (const float*)d_in[1];
    const float* conv_w = (const float*)d_in[2];
    const float* fc_w   = (const float*)d_in[3];
    const float* fc_b   = (const float*)d_in[4];
    float* out = (float*)d_out;

    float* s_ws = (float*)d_ws;                                   // 16KB
    unsigned short* wt = (unsigned short*)((char*)d_ws + 16384);  // 1.125 MB

    hipFuncSetAttribute(reinterpret_cast<const void*>(modconv_kernel),
                        hipFuncAttributeMaxDynamicSharedMemorySize, LDS_BYTES);

    style_fc_kernel<<<NB, COUT, 0, stream>>>(style, fc_w, fc_b, s_ws);
    wt_transform_kernel<<<COUT, 256, 0, stream>>>(conv_w, wt);
    modconv_kernel<<<NBLK, 512, LDS_BYTES, stream>>>(x, wt, s_ws, out);
}